// Round 1
// baseline (122.358 us; speedup 1.0000x reference)
//
#include <hip/hip_runtime.h>
#include <math.h>

#define N       4096
#define NPARAM  15
#define BI      256      // i-rows per block (one per thread)
#define NJ      16       // j-slices
#define BJ      (N / NJ) // 256 j's per slice

// d_ws layout:
//   P: [N][8] floats  (t, ra, dec, psi, mc, f_isco, dist, pad)   offset 0
//   X: [N][8] floats  (pairwise feature sums, atomic accum)      offset N*8
#define P_OFF 0
#define X_OFF (N * 8)

__global__ __launch_bounds__(256) void precompute_kernel(
    const float* __restrict__ p, float* __restrict__ ws) {
  int i = blockIdx.x * blockDim.x + threadIdx.x;
  if (i >= N) return;
  const float* r = p + i * NPARAM;
  float m1 = r[0] * 95.0f + 5.0f;
  float m2 = r[1] * 95.0f + 5.0f;
  float msum = m1 + m2;
  // mc = (m1*m2)^0.6 / (m1+m2)^0.2
  float mc = expf(0.6f * logf(m1 * m2) - 0.2f * logf(msum));
  float f_isco = 220.0f / msum;
  float dist = r[2] * 2950.0f + 50.0f;
  float* P = ws + P_OFF + i * 8;
  P[0] = r[5];   // t
  P[1] = r[3];   // ra
  P[2] = r[4];   // dec
  P[3] = r[7];   // psi
  P[4] = mc;
  P[5] = f_isco;
  P[6] = dist;
  P[7] = 0.0f;
  // zero the accumulator region (ws is re-poisoned before every call)
  float* X = ws + X_OFF + i * 8;
#pragma unroll
  for (int k = 0; k < 8; k++) X[k] = 0.0f;
}

__global__ __launch_bounds__(256) void pairwise_kernel(float* __restrict__ ws) {
  __shared__ float sh[BJ * 8];
  const float* P = ws + P_OFF;
  float* X = ws + X_OFF;
  int ib = blockIdx.x;  // 0..N/BI-1
  int jb = blockIdx.y;  // 0..NJ-1
  int t  = threadIdx.x;
  int i  = ib * BI + t;

  // stage j-slice into LDS: 256 points x 8 floats = 8 KB
  {
    const float4* src = (const float4*)(P + (size_t)jb * BJ * 8);
    float4* dst = (float4*)sh;
    dst[t * 2]     = src[t * 2];
    dst[t * 2 + 1] = src[t * 2 + 1];
  }
  __syncthreads();

  // my i-point
  float4 pi0 = ((const float4*)(P + (size_t)i * 8))[0];
  float4 pi1 = ((const float4*)(P + (size_t)i * 8))[1];
  float ti = pi0.x, rai = pi0.y, deci = pi0.z, psii = pi0.w;
  float mci = pi1.x, fi = pi1.y, di = pi1.z;

  float s0 = 0.f, s1 = 0.f, s2 = 0.f, s3 = 0.f,
        s4 = 0.f, s5 = 0.f, s6 = 0.f, s7 = 0.f;

#pragma unroll 4
  for (int j = 0; j < BJ; j++) {
    float4 a0 = ((const float4*)sh)[j * 2];       // t, ra, dec, psi
    float4 a1 = ((const float4*)sh)[j * 2 + 1];   // mc, f, dist, pad
    float dt   = fabsf(ti - a0.x);
    float dra  = fabsf(rai - a0.y);
    float ddec = fabsf(deci - a0.z);
    float dpsi = fabsf(psii - a0.w);
    float sky  = sqrtf(dra * dra + ddec * ddec);
    float msim = 30.0f * __builtin_amdgcn_rcpf(30.0f + fabsf(mci - a1.x));
    float fov  = __expf(-0.01f * fabsf(fi - a1.y));
    float lo   = fminf(di, a1.z);
    float hi   = fmaxf(di, a1.z);
    float drat = lo * __builtin_amdgcn_rcpf(hi);
    s0 += dt;  s1 += sky;  s2 += msim; s3 += fov;
    s4 += drat; s5 += dpsi; s6 += dra; s7 += ddec;
  }

  float* xi = X + (size_t)i * 8;
  atomicAdd(xi + 0, s0); atomicAdd(xi + 1, s1);
  atomicAdd(xi + 2, s2); atomicAdd(xi + 3, s3);
  atomicAdd(xi + 4, s4); atomicAdd(xi + 5, s5);
  atomicAdd(xi + 6, s6); atomicAdd(xi + 7, s7);
}

__global__ __launch_bounds__(256) void mlp_kernel(
    const float* __restrict__ ws,
    const float* __restrict__ W1, const float* __restrict__ b1,
    const float* __restrict__ ln_g, const float* __restrict__ ln_b,
    const float* __restrict__ W2, const float* __restrict__ b2,
    float* __restrict__ out) {
  __shared__ float sW1[8 * 32], sW2[32 * 16];
  __shared__ float sb1[32], sg[32], sbb[32], sb2[16];
  int t = threadIdx.x;
  if (t < 256) sW1[t] = W1[t];
  for (int k = t; k < 512; k += 256) sW2[k] = W2[k];
  if (t < 32) { sb1[t] = b1[t]; sg[t] = ln_g[t]; sbb[t] = ln_b[t]; }
  if (t < 16) sb2[t] = b2[t];
  __syncthreads();

  int i = blockIdx.x * blockDim.x + t;
  if (i >= N) return;

  const float diag[8] = {0.f, 0.f, 1.f, 1.f, 1.f, 0.f, 0.f, 0.f};
  const float inv_nm1 = 1.0f / (float)(N - 1);
  float x[8];
  const float* Xi = ws + X_OFF + (size_t)i * 8;
#pragma unroll
  for (int k = 0; k < 8; k++) x[k] = (Xi[k] - diag[k]) * inv_nm1;

  float h[32];
#pragma unroll
  for (int o = 0; o < 32; o++) {
    float a = sb1[o];
#pragma unroll
    for (int k = 0; k < 8; k++) a += x[k] * sW1[k * 32 + o];
    h[o] = a;
  }

  float mu = 0.f;
#pragma unroll
  for (int o = 0; o < 32; o++) mu += h[o];
  mu *= (1.0f / 32.0f);
  float var = 0.f;
#pragma unroll
  for (int o = 0; o < 32; o++) { float d = h[o] - mu; var += d * d; }
  var *= (1.0f / 32.0f);
  float inv = rsqrtf(var + 1e-5f);

#pragma unroll
  for (int o = 0; o < 32; o++) {
    float hn = (h[o] - mu) * inv * sg[o] + sbb[o];
    // exact GELU: 0.5*x*(1+erf(x/sqrt(2)))
    h[o] = 0.5f * hn * (1.0f + erff(hn * 0.70710678118654752f));
  }

  float* oi = out + (size_t)i * 16;
#pragma unroll
  for (int o = 0; o < 16; o++) {
    float a = sb2[o];
#pragma unroll
    for (int k = 0; k < 32; k++) a += h[k] * sW2[k * 16 + o];
    oi[o] = a;
  }
}

extern "C" void kernel_launch(void* const* d_in, const int* in_sizes, int n_in,
                              void* d_out, int out_size, void* d_ws, size_t ws_size,
                              hipStream_t stream) {
  const float* p    = (const float*)d_in[0];
  const float* W1   = (const float*)d_in[1];
  const float* b1   = (const float*)d_in[2];
  const float* ln_g = (const float*)d_in[3];
  const float* ln_b = (const float*)d_in[4];
  const float* W2   = (const float*)d_in[5];
  const float* b2   = (const float*)d_in[6];
  float* out = (float*)d_out;
  float* ws  = (float*)d_ws;

  precompute_kernel<<<N / 256, 256, 0, stream>>>(p, ws);
  dim3 grid(N / BI, NJ);
  pairwise_kernel<<<grid, 256, 0, stream>>>(ws);
  mlp_kernel<<<N / 256, 256, 0, stream>>>(ws, W1, b1, ln_g, ln_b, W2, b2, out);
}